// Round 14
// baseline (254.375 us; speedup 1.0000x reference)
//
#include <hip/hip_runtime.h>

// ============================================================================
// ContDecoder on MI355X — bf16 MFMA, round 16: deepen n-sharing to 1m x 4n
// (MG=4) in L1..L5 on the r15 structure (first confirmed win: 145->135us).
// 1024 threads (16 waves), 78.8 KB dynamic LDS, 2 blocks/CU.
//
// r15 validated the sharing axis: A shared across n-tiles + W shared across
// sibling m-waves (L1$) at full TLP = -7%. r16 doubles the sharing factor
// where the FLOPs are (L1=66%, L2=17%): wave = (mg in 0..3, ng) owns ONE
// m-tile and NPW n-tiles at stride NGRP=4. Per L1 k-step: 1 A-read -> 4
// MFMAs; W frags L1$-shared across 4 mg-waves. Per-block A-reads
// 1136 -> ~670 (-40%), wave-parallelism equal or better in every layer
// (L3 8->16, L4 4->8, L5 2->4 active waves).
// L0/L6 keep r15's 2m x 2n paths (L0 = 9% of FLOPs).
// Kept verified: in-place row [xin 0..64 | H 64..608 | 616) with pack
// zero-masking, swapped mfma(W,X)->D[n,pt], ds_write_b64 epilogue,
// float4 bias, 16x16x32 pack (r4..r15).
// ============================================================================

#define NTH     1024
#define NWAVES  16
#define MPTS    64              // points per block (4 m-tiles of 16)
#define MTILES  (MPTS / 16)
#define SROW    616             // LDS row stride in bf16 elems (1232 B)
#define XIN_OFF 0
#define HSEG    64              // H region: [64, 608)
#define NPOINTS (8 * 16384)
#define GRIDX   (NPOINTS / MPTS)   // 2048 blocks
#define LDSBYTES (MPTS * SROW * 2) // 78848 -> 2 blocks/CU

typedef short          short8  __attribute__((ext_vector_type(8)));
typedef short          short4v __attribute__((ext_vector_type(4)));
typedef float          f32x4   __attribute__((ext_vector_type(4)));
typedef unsigned short u16;

__device__ __forceinline__ u16 f2bf(float f) {
    unsigned int u = __builtin_bit_cast(unsigned int, f);
    u += 0x7fffu + ((u >> 16) & 1u);        // round-to-nearest-even
    return (u16)(u >> 16);
}

// ---------------------------------------------------------------------------
// Packed-weight geometry (16B fragments of 8 bf16). frag (l, nt, s, lane)
// holds B[s*32 + (lane>>4)*8 + j][nt*16 + (lane&15)], j=0..7, zero-padded
// outside (kact, nact) — zero k-rows mask stale in-place data.
// Identical pack as r4..r15 (HW-verified swapped-operand layout).
//   l : KHpad KSteps Ntiles  frag_base
//   0 :    0    2     33        0
//   1 :  544   19     16     4224
//   2 :  256   10      8    23680
//   3 :  128    6      4    28800
//   4 :   64    4      2    30336
//   5 :   32    3      1    30848
//   6 :   32    1      1    31040   total 31104 frags = 497664 B in d_ws
// ---------------------------------------------------------------------------
__constant__ int pk_base8[8] = {0, 4224, 23680, 28800, 30336, 30848, 31040, 31104};
__constant__ int pk_ks[7]    = {2, 19, 10, 6, 4, 3, 1};
__constant__ int pk_khp[7]   = {0, 544, 256, 128, 64, 32, 32};
__constant__ int pk_kact[7]  = {0, 516, 256, 128, 64, 32, 16};
__constant__ int pk_nact[7]  = {516, 256, 128, 64, 32, 16, 2};

struct WPtrs { const float* W[7]; };

__global__ void pack_weights(WPtrs wp, u16* __restrict__ out)
{
    const int f = blockIdx.x * blockDim.x + threadIdx.x;
    if (f >= 31104) return;
    int l = 0;
    while (l < 6 && f >= pk_base8[l + 1]) ++l;
    const int r    = f - pk_base8[l];
    const int lane = r & 63;
    const int t    = r >> 6;
    const int ks   = pk_ks[l];
    const int s    = t % ks;
    const int nt   = t / ks;
    const int n    = nt * 16 + (lane & 15);
    const int k0   = s * 32 + (lane >> 4) * 8;
    const int nact = pk_nact[l];
    const int khp  = pk_khp[l];
    const int kact = pk_kact[l];
    const float* W = wp.W[l];

    union { short8 v; u16 e[8]; } frag;
#pragma unroll
    for (int j = 0; j < 8; ++j) {
        const int k = k0 + j;
        float v = 0.0f;
        if (n < nact) {
            if (k < khp) {
                if (k < kact) v = W[k * nact + n];
            } else {
                const int xr = k - khp;
                if (xr < 37) v = W[(kact + xr) * nact + n];
            }
        }
        frag.e[j] = f2bf(v);
    }
    *(short8*)(out + (size_t)f * 8) = frag.v;
}

struct MainParams {
    const float* lr;     // [B,2,64,64]
    const float* ctx;    // [B,32,64,64]
    const float* eps;    // [B,64,64]
    const float* coord;  // [B,N,2]
    const float* Bb[7];  // biases (fp32)
    const u16*   wpack;  // packed bf16 weights in d_ws
    float*       out;    // [B,N,2]
};

// ---------------------------------------------------------------------------
// Store one n-tile's outputs for MS m-tiles starting at mbase.
// D (swapped operands): col pt = lane&15, row n = (lane>>4)*4 + r.
// ---------------------------------------------------------------------------
template<int NACT, bool RELU, int MS>
__device__ __forceinline__ void store_nt(const f32x4* accm,   // [MS]
                                         const float* __restrict__ bias,
                                         u16* __restrict__ s_act,
                                         int nt, int mbase, int lm, int lq)
{
    const int bn = nt * 16 + lq * 4;
    float bv[4];
    if (bn + 4 <= NACT) {
        const f32x4 b4 = *(const f32x4*)(bias + bn);
        bv[0] = b4[0]; bv[1] = b4[1]; bv[2] = b4[2]; bv[3] = b4[3];
    } else {
#pragma unroll
        for (int r = 0; r < 4; ++r)
            bv[r] = (bn + r < NACT) ? bias[bn + r] : 0.f;
    }
#pragma unroll
    for (int m = 0; m < MS; ++m) {
        short4v o;
#pragma unroll
        for (int r = 0; r < 4; ++r) {
            float v = accm[m][r] + bv[r];
            if (RELU) v = fmaxf(v, 0.f);
            o[r] = (short)f2bf(v);
        }
        *(short4v*)(s_act + (size_t)((mbase + m) * 16 + lm) * SROW + HSEG + bn) = o;
    }
}

#define ABOFF_(s_, KHS_) (((s_) < (KHS_)) ? (HSEG + (s_) * 32) \
                                          : (XIN_OFF + ((s_) - (KHS_)) * 32))

// ---------------------------------------------------------------------------
// Generic in-place layer, MG m-groups x NPW n-tiles per wave.
// wave -> (mg = wave & (MG-1), ng = wave >> log2(MG)); wave owns m-tiles
// [mg*MS, mg*MS+MS) and n-tiles {ng + NGRP*i}, NGRP = NWAVES/MG.
// Per k-step: MS A-reads feed NPW*MS MFMAs; W frags L1$-shared across the
// MG sibling mg-waves. compute -> barrier -> overwrite input region.
// ---------------------------------------------------------------------------
template<int KHP, int NT, int NACT, int LBASE, int MG, int NPW>
__device__ __forceinline__ void mlayer_ip(const u16* __restrict__ wpack,
                                          const float* __restrict__ bias,
                                          u16* __restrict__ s_act,
                                          int wave, int lane)
{
    constexpr int KHS  = KHP / 32;
    constexpr int KS   = KHS + 2;
    constexpr int L2MG = (MG == 1) ? 0 : (MG == 2) ? 1 : 2;
    constexpr int NGRP = NWAVES / MG;
    constexpr int MS   = MTILES / MG;
    const int lm = lane & 15;
    const int lq = lane >> 4;
    const int mg = wave & (MG - 1);
    const int ng = wave >> L2MG;
    const int mbase = mg * MS;

    const u16* arow[MS];
#pragma unroll
    for (int m = 0; m < MS; ++m)
        arow[m] = s_act + (size_t)((mbase + m) * 16 + lm) * SROW + lq * 8;
    const u16* wl = wpack + LBASE + lane * 8;

    f32x4 acc[NPW][MS];
#pragma unroll
    for (int i = 0; i < NPW; ++i)
#pragma unroll
        for (int m = 0; m < MS; ++m)
            acc[i][m] = (f32x4){0.f, 0.f, 0.f, 0.f};

    const bool act0 = (ng < NT);           // nt_i = ng + NGRP*i; i>0 active
                                           // iff compile-time NGRP*i < NT-? :
                                           // for our configs all i share act0
    if (act0) {
        const u16* bp[NPW];
#pragma unroll
        for (int i = 0; i < NPW; ++i)
            bp[i] = wl + (size_t)(ng + NGRP * i) * KS * 512;

#pragma unroll
        for (int s = 0; s < KS; ++s) {
            const int ab = ABOFF_(s, KHS);
            short8 a[MS];
#pragma unroll
            for (int m = 0; m < MS; ++m)
                a[m] = *(const short8*)(arow[m] + ab);
#pragma unroll
            for (int i = 0; i < NPW; ++i) {
                if (NGRP * i < NT) {       // compile-time for i; ng<NT given
                    const short8 w = *(const short8*)(bp[i] + (size_t)s * 512);
#pragma unroll
                    for (int m = 0; m < MS; ++m)
                        acc[i][m] = __builtin_amdgcn_mfma_f32_16x16x32_bf16(
                                        w, a[m], acc[i][m], 0, 0, 0);
                }
            }
        }
    }
    __syncthreads();                       // all reads done before overwrite
    if (act0) {
#pragma unroll
        for (int i = 0; i < NPW; ++i)
            if (NGRP * i < NT)
                store_nt<NACT, true, MS>(acc[i], bias, s_act,
                                         ng + NGRP * i, mbase, lm, lq);
    }
}

__global__ __launch_bounds__(NTH, 8)   // 8 waves/EU = 32 waves/CU = 2 blocks
void cont_decoder_mfma(MainParams p)
{
    extern __shared__ u16 s_act[];         // MPTS*SROW bf16 = 78848 B
    __shared__ int   s_x0[MPTS], s_y0[MPTS];
    __shared__ float s_wx[MPTS], s_wy[MPTS];

    const int tid  = threadIdx.x;
    const int wave = tid >> 6;
    const int lane = tid & 63;
    const int lm   = lane & 15;
    const int lq   = lane >> 4;
    const int p0   = blockIdx.x * MPTS;
    const int b    = p0 >> 14;             // 16384 points per batch

    // ---- zero pad regions: xin[37..64) and H tail [592..608) ----
    for (int i = tid; i < MPTS * 43; i += NTH) {
        const int pt = i / 43, c = i % 43;
        const int col = (c < 27) ? (37 + c) : (592 + (c - 27));
        s_act[pt * SROW + col] = 0;
    }

    // ---- bilinear params + coord features ----
    if (tid < MPTS) {
        const int pt = p0 + tid;
        const float cx = p.coord[2 * pt];
        const float cy = p.coord[2 * pt + 1];
        const float gx = (cx + 1.0f) * 32.0f - 0.5f;   // align_corners=False
        const float gy = (cy + 1.0f) * 32.0f - 0.5f;
        const float fx0 = floorf(gx), fy0 = floorf(gy);
        s_x0[tid] = (int)fx0;
        s_y0[tid] = (int)fy0;
        s_wx[tid] = gx - fx0;
        s_wy[tid] = gy - fy0;
        s_act[tid * SROW + 32] = f2bf(cx);
        s_act[tid * SROW + 33] = f2bf(cy);
    }
    __syncthreads();

    // ---- sample 35 channels/point (ref swaps spatial axes: val = g[b,c,x,y]) ----
    for (int idx = tid; idx < MPTS * 35; idx += NTH) {
        const int t = idx / 35;
        const int c = idx % 35;
        const float* base;
        int col;
        if (c < 32)      { base = p.ctx + (size_t)(b * 32 + c) * 4096;       col = c; }
        else if (c < 34) { base = p.lr  + (size_t)(b * 2 + (c - 32)) * 4096; col = 34 + (c - 32); }
        else             { base = p.eps + (size_t)b * 4096;                   col = 36; }

        const int   x0 = s_x0[t], y0 = s_y0[t];
        const float wx = s_wx[t], wy = s_wy[t];
        const int x1 = x0 + 1, y1 = y0 + 1;
        const bool xv0 = (x0 >= 0) & (x0 < 64);
        const bool xv1 = (x1 >= 0) & (x1 < 64);
        const bool yv0 = (y0 >= 0) & (y0 < 64);
        const bool yv1 = (y1 >= 0) & (y1 < 64);
        const int xc0 = min(max(x0, 0), 63), xc1 = min(max(x1, 0), 63);
        const int yc0 = min(max(y0, 0), 63), yc1 = min(max(y1, 0), 63);

        const float w00 = (1.0f - wx) * (1.0f - wy) * ((xv0 && yv0) ? 1.0f : 0.0f);
        const float w10 = wx * (1.0f - wy)          * ((xv1 && yv0) ? 1.0f : 0.0f);
        const float w01 = (1.0f - wx) * wy          * ((xv0 && yv1) ? 1.0f : 0.0f);
        const float w11 = wx * wy                   * ((xv1 && yv1) ? 1.0f : 0.0f);

        const float val = w00 * base[xc0 * 64 + yc0]
                        + w10 * base[xc1 * 64 + yc0]
                        + w01 * base[xc0 * 64 + yc1]
                        + w11 * base[xc1 * 64 + yc1];
        s_act[t * SROW + col] = f2bf(val);
    }
    __syncthreads();

    // ---- per-wave 2m pair pointers for L0/L6 (r15 mapping: mg=wave&1) ----
    {
        const int mgp   = wave & 1;
        const int ngp   = wave >> 1;
        const int mbase = mgp * 2;
        const u16* arow0 = s_act + (size_t)(mbase * 16 + lm) * SROW + lq * 8;
        const u16* arow1 = arow0 + (size_t)16 * SROW;

        // ---- L0: reads xin only, writes H [64,592) — disjoint (r15 path) ----
        const u16* wl0 = p.wpack + 0 + lane * 8;
        for (int g = 0;; ++g) {
            const int nt0 = ngp + 16 * g;
            if (nt0 >= 33) break;
            const int nt1 = nt0 + 8;
            const bool act1 = nt1 < 33;
            f32x4 acc[2][2];
#pragma unroll
            for (int i = 0; i < 2; ++i)
#pragma unroll
                for (int m = 0; m < 2; ++m)
                    acc[i][m] = (f32x4){0.f, 0.f, 0.f, 0.f};
            const u16* bp0 = wl0 + (size_t)nt0 * 2 * 512;
            const u16* bp1 = wl0 + (size_t)nt1 * 2 * 512;
#pragma unroll
            for (int s = 0; s < 2; ++s) {
                const int ab = XIN_OFF + s * 32;
                const short8 a0 = *(const short8*)(arow0 + ab);
                const short8 a1 = *(const short8*)(arow1 + ab);
                const short8 w0 = *(const short8*)(bp0 + (size_t)s * 512);
                acc[0][0] = __builtin_amdgcn_mfma_f32_16x16x32_bf16(w0, a0, acc[0][0], 0, 0, 0);
                acc[0][1] = __builtin_amdgcn_mfma_f32_16x16x32_bf16(w0, a1, acc[0][1], 0, 0, 0);
                if (act1) {
                    const short8 w1 = *(const short8*)(bp1 + (size_t)s * 512);
                    acc[1][0] = __builtin_amdgcn_mfma_f32_16x16x32_bf16(w1, a0, acc[1][0], 0, 0, 0);
                    acc[1][1] = __builtin_amdgcn_mfma_f32_16x16x32_bf16(w1, a1, acc[1][1], 0, 0, 0);
                }
            }
            store_nt<516, true, 2>(acc[0], p.Bb[0], s_act, nt0, mbase, lm, lq);
            if (act1)
                store_nt<516, true, 2>(acc[1], p.Bb[0], s_act, nt1, mbase, lm, lq);
        }
    }
    __syncthreads();

    // ---- L1..L5: generic in-place, MG=4 (1 m-tile/wave), deep n-share ----
    //           KHP  NT  NACT LBASE   MG NPW
    mlayer_ip< 544, 16, 256, 33792,  4, 4>(p.wpack, p.Bb[1], s_act, wave, lane);
    __syncthreads();
    mlayer_ip< 256,  8, 128, 189440, 4, 2>(p.wpack, p.Bb[2], s_act, wave, lane);
    __syncthreads();
    mlayer_ip< 128,  4,  64, 230400, 4, 1>(p.wpack, p.Bb[3], s_act, wave, lane);
    __syncthreads();
    mlayer_ip<  64,  2,  32, 242688, 4, 1>(p.wpack, p.Bb[4], s_act, wave, lane);
    __syncthreads();
    mlayer_ip<  32,  1,  16, 246784, 4, 1>(p.wpack, p.Bb[5], s_act, wave, lane);
    __syncthreads();

    // ---- L6: reads H [64,96) (k 16..31 zero-masked), global out (r15) ----
    if ((wave >> 1) == 0) {                // waves 0,1 cover all 4 m-tiles
        const int mgp   = wave & 1;
        const int mbase = mgp * 2;
        const u16* arow0 = s_act + (size_t)(mbase * 16 + lm) * SROW + lq * 8;
        const u16* arow1 = arow0 + (size_t)16 * SROW;
        f32x4 acc[2];
        acc[0] = (f32x4){0.f, 0.f, 0.f, 0.f};
        acc[1] = (f32x4){0.f, 0.f, 0.f, 0.f};
        const u16* bp = p.wpack + 248320 + lane * 8;
        const short8 w0 = *(const short8*)(bp);
        const int ab = HSEG;
        const short8 a0 = *(const short8*)(arow0 + ab);
        const short8 a1 = *(const short8*)(arow1 + ab);
        acc[0] = __builtin_amdgcn_mfma_f32_16x16x32_bf16(w0, a0, acc[0], 0, 0, 0);
        acc[1] = __builtin_amdgcn_mfma_f32_16x16x32_bf16(w0, a1, acc[1], 0, 0, 0);
        if (lq == 0) {
            const float b0 = p.Bb[6][0], b1 = p.Bb[6][1];
#pragma unroll
            for (int m = 0; m < 2; ++m) {
                float2 o;
                o.x = acc[m][0] + b0;
                o.y = acc[m][1] + b1;
                *(float2*)(p.out + (size_t)(p0 + (mbase + m) * 16 + lm) * 2) = o;
            }
        }
    }
}

extern "C" void kernel_launch(void* const* d_in, const int* in_sizes, int n_in,
                              void* d_out, int out_size, void* d_ws, size_t ws_size,
                              hipStream_t stream)
{
    WPtrs wp;
    for (int l = 0; l < 7; ++l) wp.W[l] = (const float*)d_in[4 + 2 * l];

    MainParams p;
    p.lr    = (const float*)d_in[0];
    p.ctx   = (const float*)d_in[1];
    p.eps   = (const float*)d_in[2];
    p.coord = (const float*)d_in[3];
    for (int l = 0; l < 7; ++l) p.Bb[l] = (const float*)d_in[5 + 2 * l];
    p.wpack = (const u16*)d_ws;
    p.out   = (float*)d_out;

    // Opt in to large dynamic LDS (idempotent; not a stream op, capture-safe).
    hipFuncSetAttribute((const void*)cont_decoder_mfma,
                        hipFuncAttributeMaxDynamicSharedMemorySize, LDSBYTES);

    hipLaunchKernelGGL(pack_weights, dim3(122), dim3(256), 0, stream, wp, (u16*)d_ws);
    hipLaunchKernelGGL(cont_decoder_mfma, dim3(GRIDX), dim3(NTH), LDSBYTES, stream, p);
}

// Round 15
// 186.984 us; speedup vs baseline: 1.3604x; 1.3604x over previous
//
#include <hip/hip_runtime.h>

// ============================================================================
// ContDecoder on MI355X — bf16 MFMA, round 17: channel-last sampling repack.
// Base = r15 (best, 135us): MPTS=64, in-place row [xin 0..64 | H 64..608 |
// 616), 2m x 2n pair-waves, 2 blocks/CU. r16's MG=4 regressed (W-issue
// doubled) -> MFMA mapping space closed at r15's MS=2 optimum
// (cost = 16cyc*W + 8cyc*A minimized).
// r17 attacks the remaining non-MFMA term: the sampling prologue's 8960
// scattered dword-gathers/block (consecutive lanes hit 16KB-apart planes ->
// 1 line/lane). Fix: repack ctx/lr/eps into channel-last [x][y][38] fp32 in
// d_ws (coalesced LDS-transpose kernel, ~5MB); sampling lanes (same point,
// consecutive channels) then read consecutive floats — ~10x less line
// traffic. Guarded by ws_size: < 5.5MB -> exact r15 fallback path.
// ============================================================================

#define NTH     1024
#define NWAVES  16
#define MPTS    64              // points per block (4 m-tiles of 16)
#define MTILES  (MPTS / 16)
#define SROW    616             // LDS row stride in bf16 elems (1232 B)
#define XIN_OFF 0
#define HSEG    64              // H region: [64, 608)
#define NPOINTS (8 * 16384)
#define GRIDX   (NPOINTS / MPTS)   // 2048 blocks
#define LDSBYTES (MPTS * SROW * 2) // 78848 -> 2 blocks/CU
#define CLSTRIDE 38             // channel-last inner stride (floats)
#define CLOFF   524288          // byte offset of channel-last block in d_ws

typedef short          short8  __attribute__((ext_vector_type(8)));
typedef short          short4v __attribute__((ext_vector_type(4)));
typedef float          f32x4   __attribute__((ext_vector_type(4)));
typedef unsigned short u16;

__device__ __forceinline__ u16 f2bf(float f) {
    unsigned int u = __builtin_bit_cast(unsigned int, f);
    u += 0x7fffu + ((u >> 16) & 1u);        // round-to-nearest-even
    return (u16)(u >> 16);
}

// ---------------------------------------------------------------------------
// Packed-weight geometry (16B fragments of 8 bf16). frag (l, nt, s, lane)
// holds B[s*32 + (lane>>4)*8 + j][nt*16 + (lane&15)], j=0..7, zero-padded
// outside (kact, nact) — zero k-rows mask stale in-place data.
// Identical pack as r4..r16 (HW-verified swapped-operand layout).
//   l : KHpad KSteps Ntiles  frag_base
//   0 :    0    2     33        0
//   1 :  544   19     16     4224
//   2 :  256   10      8    23680
//   3 :  128    6      4    28800
//   4 :   64    4      2    30336
//   5 :   32    3      1    30848
//   6 :   32    1      1    31040   total 31104 frags = 497664 B in d_ws
// ---------------------------------------------------------------------------
__constant__ int pk_base8[8] = {0, 4224, 23680, 28800, 30336, 30848, 31040, 31104};
__constant__ int pk_ks[7]    = {2, 19, 10, 6, 4, 3, 1};
__constant__ int pk_khp[7]   = {0, 544, 256, 128, 64, 32, 32};
__constant__ int pk_kact[7]  = {0, 516, 256, 128, 64, 32, 16};
__constant__ int pk_nact[7]  = {516, 256, 128, 64, 32, 16, 2};

struct WPtrs { const float* W[7]; };

__global__ void pack_weights(WPtrs wp, u16* __restrict__ out)
{
    const int f = blockIdx.x * blockDim.x + threadIdx.x;
    if (f >= 31104) return;
    int l = 0;
    while (l < 6 && f >= pk_base8[l + 1]) ++l;
    const int r    = f - pk_base8[l];
    const int lane = r & 63;
    const int t    = r >> 6;
    const int ks   = pk_ks[l];
    const int s    = t % ks;
    const int nt   = t / ks;
    const int n    = nt * 16 + (lane & 15);
    const int k0   = s * 32 + (lane >> 4) * 8;
    const int nact = pk_nact[l];
    const int khp  = pk_khp[l];
    const int kact = pk_kact[l];
    const float* W = wp.W[l];

    union { short8 v; u16 e[8]; } frag;
#pragma unroll
    for (int j = 0; j < 8; ++j) {
        const int k = k0 + j;
        float v = 0.0f;
        if (n < nact) {
            if (k < khp) {
                if (k < kact) v = W[k * nact + n];
            } else {
                const int xr = k - khp;
                if (xr < 37) v = W[(kact + xr) * nact + n];
            }
        }
        frag.e[j] = f2bf(v);
    }
    *(short8*)(out + (size_t)f * 8) = frag.v;
}

// ---------------------------------------------------------------------------
// Channel-last repack: cl[b][x][y][slot] = plane_c[b][x][y], slot = xin col
// (ctx c -> c; lr c -> 34+c; eps -> 36; slots 32,33,37 zero). One block per
// (b, x): coalesced plane-row reads -> LDS transpose -> contiguous write.
// ---------------------------------------------------------------------------
struct RPk { const float* ctx; const float* lr; const float* eps; float* cl; };

__global__ void repack_cl(RPk q)
{
    __shared__ float ls[64 * CLSTRIDE];
    const int b = blockIdx.x >> 6;
    const int x = blockIdx.x & 63;
    for (int i = threadIdx.x; i < 64 * CLSTRIDE; i += 256) ls[i] = 0.f;
    __syncthreads();
    for (int i = threadIdx.x; i < 35 * 64; i += 256) {
        const int c = i / 64, y = i % 64;
        float v; int slot;
        if (c < 32)      { v = q.ctx[(((size_t)b * 32 + c) * 64 + x) * 64 + y]; slot = c; }
        else if (c < 34) { v = q.lr [(((size_t)b * 2 + (c - 32)) * 64 + x) * 64 + y]; slot = 34 + (c - 32); }
        else             { v = q.eps[(((size_t)b) * 64 + x) * 64 + y];          slot = 36; }
        ls[y * CLSTRIDE + slot] = v;
    }
    __syncthreads();
    float* out = q.cl + ((size_t)b * 64 + x) * 64 * CLSTRIDE;
    for (int i = threadIdx.x; i < 64 * CLSTRIDE; i += 256) out[i] = ls[i];
}

struct MainParams {
    const float* lr;     // [B,2,64,64]
    const float* ctx;    // [B,32,64,64]
    const float* eps;    // [B,64,64]
    const float* coord;  // [B,N,2]
    const float* Bb[7];  // biases (fp32)
    const u16*   wpack;  // packed bf16 weights in d_ws
    const float* cl;     // channel-last planes (d_ws + CLOFF), if clok
    int          clok;   // 1 -> cl path valid
    float*       out;    // [B,N,2]
};

// ---------------------------------------------------------------------------
// Store one n-tile's outputs for the wave's 2 m-tiles.
// D (swapped operands): col pt = lane&15, row n = (lane>>4)*4 + r.
// ---------------------------------------------------------------------------
template<int NACT, bool RELU>
__device__ __forceinline__ void store_nt(const f32x4* accm,   // [2] m-pair
                                         const float* __restrict__ bias,
                                         u16* __restrict__ s_act,
                                         int nt, int mbase, int lm, int lq)
{
    const int bn = nt * 16 + lq * 4;
    float bv[4];
    if (bn + 4 <= NACT) {
        const f32x4 b4 = *(const f32x4*)(bias + bn);
        bv[0] = b4[0]; bv[1] = b4[1]; bv[2] = b4[2]; bv[3] = b4[3];
    } else {
#pragma unroll
        for (int r = 0; r < 4; ++r)
            bv[r] = (bn + r < NACT) ? bias[bn + r] : 0.f;
    }
#pragma unroll
    for (int m = 0; m < 2; ++m) {
        short4v o;
#pragma unroll
        for (int r = 0; r < 4; ++r) {
            float v = accm[m][r] + bv[r];
            if (RELU) v = fmaxf(v, 0.f);
            o[r] = (short)f2bf(v);
        }
        *(short4v*)(s_act + (size_t)((mbase + m) * 16 + lm) * SROW + HSEG + bn) = o;
    }
}

// ---------------------------------------------------------------------------
// One MLP layer, (mg, ng) pair-wave mapping (r15, verified 135us). mg=wave&1
// owns m-tiles {2mg, 2mg+1}; ng=wave>>1 owns n-tiles {ng, ng+8, ...} < NT.
// Per K-step: 2 ds_read (A, shared across n-pair) + <=2 global loads (W,
// L1$-shared across the 2 sibling mg-waves) + <=4 MFMA (swapped: D[n,pt]).
// IPBAR: in-place layer — compute all, barrier, overwrite input.
// ---------------------------------------------------------------------------
template<int KHP, int NT, int NACT, int LBASE,
         bool XIN, bool RELU, bool GOUT, bool IPBAR>
__device__ __forceinline__ void mlayer(const u16* __restrict__ wpack,
                                       const float* __restrict__ bias,
                                       u16* __restrict__ s_act,
                                       float* __restrict__ gout, int p0,
                                       int wave, int lane)
{
    constexpr int KHS = KHP / 32;
    constexpr int KS  = KHS + (XIN ? 2 : 0);
    const int lm = lane & 15;
    const int lq = lane >> 4;
    const int mg = wave & 1;
    const int ng = wave >> 1;          // 0..7
    const int mbase = mg * 2;          // m-tiles {mbase, mbase+1}

    const u16* arow0 = s_act + (size_t)((mbase * 16) + lm) * SROW + lq * 8;
    const u16* arow1 = arow0 + (size_t)16 * SROW;
    const u16* wl = wpack + LBASE + lane * 8;

#define ABOFF(s_) (((s_) < KHS) ? (HSEG + (s_) * 32) : (XIN_OFF + ((s_) - KHS) * 32))

    if constexpr (IPBAR) {
        const int nt0 = ng, nt1 = ng + 8;
        const bool act0 = nt0 < NT;
        const bool act1 = nt1 < NT;
        f32x4 acc[2][2];
#pragma unroll
        for (int i = 0; i < 2; ++i)
#pragma unroll
            for (int m = 0; m < 2; ++m)
                acc[i][m] = (f32x4){0.f, 0.f, 0.f, 0.f};

        if (act0) {
            const u16* bp0 = wl + (size_t)nt0 * KS * 512;
            const u16* bp1 = wl + (size_t)nt1 * KS * 512;
#pragma unroll
            for (int s = 0; s < KS; ++s) {
                const int ab = ABOFF(s);
                const short8 a0 = *(const short8*)(arow0 + ab);
                const short8 a1 = *(const short8*)(arow1 + ab);
                const short8 w0 = *(const short8*)(bp0 + (size_t)s * 512);
                acc[0][0] = __builtin_amdgcn_mfma_f32_16x16x32_bf16(w0, a0, acc[0][0], 0, 0, 0);
                acc[0][1] = __builtin_amdgcn_mfma_f32_16x16x32_bf16(w0, a1, acc[0][1], 0, 0, 0);
                if (act1) {
                    const short8 w1 = *(const short8*)(bp1 + (size_t)s * 512);
                    acc[1][0] = __builtin_amdgcn_mfma_f32_16x16x32_bf16(w1, a0, acc[1][0], 0, 0, 0);
                    acc[1][1] = __builtin_amdgcn_mfma_f32_16x16x32_bf16(w1, a1, acc[1][1], 0, 0, 0);
                }
            }
        }
        __syncthreads();                   // all reads done before overwrite
        if (act0) store_nt<NACT, RELU>(acc[0], bias, s_act, nt0, mbase, lm, lq);
        if (act1) store_nt<NACT, RELU>(acc[1], bias, s_act, nt1, mbase, lm, lq);
    } else {
        for (int g = 0;; ++g) {
            const int nt0 = ng + 16 * g;
            if (nt0 >= NT) break;
            const int nt1 = nt0 + 8;
            const bool act1 = nt1 < NT;
            f32x4 acc[2][2];
#pragma unroll
            for (int i = 0; i < 2; ++i)
#pragma unroll
                for (int m = 0; m < 2; ++m)
                    acc[i][m] = (f32x4){0.f, 0.f, 0.f, 0.f};

            const u16* bp0 = wl + (size_t)nt0 * KS * 512;
            const u16* bp1 = wl + (size_t)nt1 * KS * 512;
#pragma unroll
            for (int s = 0; s < KS; ++s) {
                const int ab = ABOFF(s);
                const short8 a0 = *(const short8*)(arow0 + ab);
                const short8 a1 = *(const short8*)(arow1 + ab);
                const short8 w0 = *(const short8*)(bp0 + (size_t)s * 512);
                acc[0][0] = __builtin_amdgcn_mfma_f32_16x16x32_bf16(w0, a0, acc[0][0], 0, 0, 0);
                acc[0][1] = __builtin_amdgcn_mfma_f32_16x16x32_bf16(w0, a1, acc[0][1], 0, 0, 0);
                if (act1) {
                    const short8 w1 = *(const short8*)(bp1 + (size_t)s * 512);
                    acc[1][0] = __builtin_amdgcn_mfma_f32_16x16x32_bf16(w1, a0, acc[1][0], 0, 0, 0);
                    acc[1][1] = __builtin_amdgcn_mfma_f32_16x16x32_bf16(w1, a1, acc[1][1], 0, 0, 0);
                }
            }

            if (GOUT) {
                if (lq == 0) {             // only n=0,1 valid (NACT=2)
                    const float b0 = bias[0], b1 = bias[1];
#pragma unroll
                    for (int m = 0; m < 2; ++m) {
                        float2 o;
                        o.x = acc[0][m][0] + b0;
                        o.y = acc[0][m][1] + b1;
                        *(float2*)(gout + (size_t)(p0 + (mbase + m) * 16 + lm) * 2) = o;
                    }
                }
            } else {
                store_nt<NACT, RELU>(acc[0], bias, s_act, nt0, mbase, lm, lq);
                if (act1)
                    store_nt<NACT, RELU>(acc[1], bias, s_act, nt1, mbase, lm, lq);
            }
        }
    }
#undef ABOFF
}

__global__ __launch_bounds__(NTH, 8)   // 8 waves/EU = 32 waves/CU = 2 blocks
void cont_decoder_mfma(MainParams p)
{
    extern __shared__ u16 s_act[];         // MPTS*SROW bf16 = 78848 B
    __shared__ int   s_x0[MPTS], s_y0[MPTS];
    __shared__ float s_wx[MPTS], s_wy[MPTS];

    const int tid  = threadIdx.x;
    const int wave = tid >> 6;
    const int lane = tid & 63;
    const int p0   = blockIdx.x * MPTS;
    const int b    = p0 >> 14;             // 16384 points per batch

    // ---- zero pad regions: xin[37..64) and H tail [592..608) ----
    for (int i = tid; i < MPTS * 43; i += NTH) {
        const int pt = i / 43, c = i % 43;
        const int col = (c < 27) ? (37 + c) : (592 + (c - 27));
        s_act[pt * SROW + col] = 0;
    }

    // ---- bilinear params + coord features ----
    if (tid < MPTS) {
        const int pt = p0 + tid;
        const float cx = p.coord[2 * pt];
        const float cy = p.coord[2 * pt + 1];
        const float gx = (cx + 1.0f) * 32.0f - 0.5f;   // align_corners=False
        const float gy = (cy + 1.0f) * 32.0f - 0.5f;
        const float fx0 = floorf(gx), fy0 = floorf(gy);
        s_x0[tid] = (int)fx0;
        s_y0[tid] = (int)fy0;
        s_wx[tid] = gx - fx0;
        s_wy[tid] = gy - fy0;
        s_act[tid * SROW + 32] = f2bf(cx);
        s_act[tid * SROW + 33] = f2bf(cy);
    }
    __syncthreads();

    // ---- sample 35 channels/point (ref swaps spatial axes: g[b,c,x,y]) ----
    if (p.clok) {
        // channel-last fast path: lanes (same t, consecutive c) read
        // consecutive floats -> coalesced 140B segments per tap.
        const float* cl = p.cl + (size_t)b * 64 * 64 * CLSTRIDE;
        for (int idx = tid; idx < MPTS * 35; idx += NTH) {
            const int t = idx / 35;
            const int c = idx % 35;
            const int col = (c < 32) ? c : 34 + (c - 32);   // == cl slot

            const int   x0 = s_x0[t], y0 = s_y0[t];
            const float wx = s_wx[t], wy = s_wy[t];
            const int x1 = x0 + 1, y1 = y0 + 1;
            const bool xv0 = (x0 >= 0) & (x0 < 64);
            const bool xv1 = (x1 >= 0) & (x1 < 64);
            const bool yv0 = (y0 >= 0) & (y0 < 64);
            const bool yv1 = (y1 >= 0) & (y1 < 64);
            const int xc0 = min(max(x0, 0), 63), xc1 = min(max(x1, 0), 63);
            const int yc0 = min(max(y0, 0), 63), yc1 = min(max(y1, 0), 63);

            const float w00 = (1.0f - wx) * (1.0f - wy) * ((xv0 && yv0) ? 1.0f : 0.0f);
            const float w10 = wx * (1.0f - wy)          * ((xv1 && yv0) ? 1.0f : 0.0f);
            const float w01 = (1.0f - wx) * wy          * ((xv0 && yv1) ? 1.0f : 0.0f);
            const float w11 = wx * wy                   * ((xv1 && yv1) ? 1.0f : 0.0f);

            const float val = w00 * cl[(size_t)(xc0 * 64 + yc0) * CLSTRIDE + col]
                            + w10 * cl[(size_t)(xc1 * 64 + yc0) * CLSTRIDE + col]
                            + w01 * cl[(size_t)(xc0 * 64 + yc1) * CLSTRIDE + col]
                            + w11 * cl[(size_t)(xc1 * 64 + yc1) * CLSTRIDE + col];
            s_act[t * SROW + col] = f2bf(val);
        }
    } else {
        // fallback: original plane-gather path (exact r15)
        for (int idx = tid; idx < MPTS * 35; idx += NTH) {
            const int t = idx / 35;
            const int c = idx % 35;
            const float* base;
            int col;
            if (c < 32)      { base = p.ctx + (size_t)(b * 32 + c) * 4096;       col = c; }
            else if (c < 34) { base = p.lr  + (size_t)(b * 2 + (c - 32)) * 4096; col = 34 + (c - 32); }
            else             { base = p.eps + (size_t)b * 4096;                   col = 36; }

            const int   x0 = s_x0[t], y0 = s_y0[t];
            const float wx = s_wx[t], wy = s_wy[t];
            const int x1 = x0 + 1, y1 = y0 + 1;
            const bool xv0 = (x0 >= 0) & (x0 < 64);
            const bool xv1 = (x1 >= 0) & (x1 < 64);
            const bool yv0 = (y0 >= 0) & (y0 < 64);
            const bool yv1 = (y1 >= 0) & (y1 < 64);
            const int xc0 = min(max(x0, 0), 63), xc1 = min(max(x1, 0), 63);
            const int yc0 = min(max(y0, 0), 63), yc1 = min(max(y1, 0), 63);

            const float w00 = (1.0f - wx) * (1.0f - wy) * ((xv0 && yv0) ? 1.0f : 0.0f);
            const float w10 = wx * (1.0f - wy)          * ((xv1 && yv0) ? 1.0f : 0.0f);
            const float w01 = (1.0f - wx) * wy          * ((xv0 && yv1) ? 1.0f : 0.0f);
            const float w11 = wx * wy                   * ((xv1 && yv1) ? 1.0f : 0.0f);

            const float val = w00 * base[xc0 * 64 + yc0]
                            + w10 * base[xc1 * 64 + yc0]
                            + w01 * base[xc0 * 64 + yc1]
                            + w11 * base[xc1 * 64 + yc1];
            s_act[t * SROW + col] = f2bf(val);
        }
    }
    __syncthreads();

    // ---- MLP:  xin(37p64) ->W0-> H(516p544) ->W1-> H(256) ->W2-> H(128)
    //            ->W3-> H(64) ->W4-> H(32) ->W5-> H(16) ->W6-> out(2)
    //     KHP  NT  NACT LBASE    XIN    RELU   GOUT   IPBAR
    mlayer<  0, 33, 516, 0,      true,  true,  false, false>(p.wpack, p.Bb[0], s_act, nullptr, p0, wave, lane);
    __syncthreads();
    mlayer<544, 16, 256, 33792,  true,  true,  false, true >(p.wpack, p.Bb[1], s_act, nullptr, p0, wave, lane);
    __syncthreads();
    mlayer<256,  8, 128, 189440, true,  true,  false, true >(p.wpack, p.Bb[2], s_act, nullptr, p0, wave, lane);
    __syncthreads();
    mlayer<128,  4,  64, 230400, true,  true,  false, true >(p.wpack, p.Bb[3], s_act, nullptr, p0, wave, lane);
    __syncthreads();
    mlayer< 64,  2,  32, 242688, true,  true,  false, true >(p.wpack, p.Bb[4], s_act, nullptr, p0, wave, lane);
    __syncthreads();
    mlayer< 32,  1,  16, 246784, true,  true,  false, true >(p.wpack, p.Bb[5], s_act, nullptr, p0, wave, lane);
    __syncthreads();
    mlayer< 32,  1,   2, 248320, false, false, true,  false>(p.wpack, p.Bb[6], s_act, p.out,   p0, wave, lane);
}

extern "C" void kernel_launch(void* const* d_in, const int* in_sizes, int n_in,
                              void* d_out, int out_size, void* d_ws, size_t ws_size,
                              hipStream_t stream)
{
    WPtrs wp;
    for (int l = 0; l < 7; ++l) wp.W[l] = (const float*)d_in[4 + 2 * l];

    const size_t cl_bytes = (size_t)8 * 64 * 64 * CLSTRIDE * 4;   // 4.98 MB
    const bool clok = ws_size >= (size_t)CLOFF + cl_bytes;

    MainParams p;
    p.lr    = (const float*)d_in[0];
    p.ctx   = (const float*)d_in[1];
    p.eps   = (const float*)d_in[2];
    p.coord = (const float*)d_in[3];
    for (int l = 0; l < 7; ++l) p.Bb[l] = (const float*)d_in[5 + 2 * l];
    p.wpack = (const u16*)d_ws;
    p.cl    = (const float*)((const char*)d_ws + CLOFF);
    p.clok  = clok ? 1 : 0;
    p.out   = (float*)d_out;

    // Opt in to large dynamic LDS (idempotent; not a stream op, capture-safe).
    hipFuncSetAttribute((const void*)cont_decoder_mfma,
                        hipFuncAttributeMaxDynamicSharedMemorySize, LDSBYTES);

    hipLaunchKernelGGL(pack_weights, dim3(122), dim3(256), 0, stream, wp, (u16*)d_ws);
    if (clok) {
        RPk q;
        q.ctx = p.ctx; q.lr = p.lr; q.eps = p.eps;
        q.cl  = (float*)((char*)d_ws + CLOFF);
        hipLaunchKernelGGL(repack_cl, dim3(512), dim3(256), 0, stream, q);
    }
    hipLaunchKernelGGL(cont_decoder_mfma, dim3(GRIDX), dim3(NTH), LDSBYTES, stream, p);
}

// Round 16
// 184.357 us; speedup vs baseline: 1.3798x; 1.0143x over previous
//
#include <hip/hip_runtime.h>

// ============================================================================
// ContDecoder on MI355X — bf16 MFMA, round 18: vectorized sampling quads +
// v_cvt_pk_bf16_f32 epilogue (VALU/issue-count cut on the r17 winner).
// Base = r17 (103.9us main): MPTS=64, in-place row [xin 0..64 | H 64..608 |
// 616), 2m x 2n pair-waves, channel-last sampling repack, 2 blocks/CU.
//
// r17 ledger: VALU 41% is now the largest busy term; sampling still scalar.
// r18 levers (layout/width class — the class that works):
//   (1) CLSTRIDE 38->40: 10 aligned float4 quads per pixel. Sampling does
//       one quad per iteration: 640 iters/block (was 2240), 4-tap float4
//       loads (16 lanes/line), 16 FMA, 2 cvt_pk, 1 ds_write_b64.
//       Quad 8 writes only cols 34,35 (preserves coord cols 32,33);
//       quad 9 writes 36-39 (37-39 are zeros in the repack = pad).
//   (2) v_cvt_pk_bf16_f32 (RNE, bit-identical to our f2bf) replaces 3-op
//       manual RNE everywhere hot: 2 values/op, ~65K values/block.
// ============================================================================

#define NTH     1024
#define NWAVES  16
#define MPTS    64              // points per block (4 m-tiles of 16)
#define MTILES  (MPTS / 16)
#define SROW    616             // LDS row stride in bf16 elems (1232 B)
#define XIN_OFF 0
#define HSEG    64              // H region: [64, 608)
#define NPOINTS (8 * 16384)
#define GRIDX   (NPOINTS / MPTS)   // 2048 blocks
#define LDSBYTES (MPTS * SROW * 2) // 78848 -> 2 blocks/CU
#define CLSTRIDE 40             // channel-last inner stride (floats, 10 quads)
#define CLOFF   524288          // byte offset of channel-last block in d_ws

typedef short          short8  __attribute__((ext_vector_type(8)));
typedef short          short4v __attribute__((ext_vector_type(4)));
typedef float          f32x4   __attribute__((ext_vector_type(4)));
typedef unsigned short u16;

__device__ __forceinline__ u16 f2bf(float f) {
    unsigned int u = __builtin_bit_cast(unsigned int, f);
    u += 0x7fffu + ((u >> 16) & 1u);        // round-to-nearest-even
    return (u16)(u >> 16);
}

// packed RNE f32x2 -> bf16x2 (dst.lo = bf16(a), dst.hi = bf16(b))
__device__ __forceinline__ unsigned cvtpk(float a, float b) {
    unsigned r;
    asm("v_cvt_pk_bf16_f32 %0, %1, %2" : "=v"(r) : "v"(a), "v"(b));
    return r;
}

// ---------------------------------------------------------------------------
// Packed-weight geometry (16B fragments of 8 bf16). frag (l, nt, s, lane)
// holds B[s*32 + (lane>>4)*8 + j][nt*16 + (lane&15)], j=0..7, zero-padded
// outside (kact, nact) — zero k-rows mask stale in-place data.
// Identical pack as r4..r17 (HW-verified swapped-operand layout).
//   l : KHpad KSteps Ntiles  frag_base
//   0 :    0    2     33        0
//   1 :  544   19     16     4224
//   2 :  256   10      8    23680
//   3 :  128    6      4    28800
//   4 :   64    4      2    30336
//   5 :   32    3      1    30848
//   6 :   32    1      1    31040   total 31104 frags = 497664 B in d_ws
// ---------------------------------------------------------------------------
__constant__ int pk_base8[8] = {0, 4224, 23680, 28800, 30336, 30848, 31040, 31104};
__constant__ int pk_ks[7]    = {2, 19, 10, 6, 4, 3, 1};
__constant__ int pk_khp[7]   = {0, 544, 256, 128, 64, 32, 32};
__constant__ int pk_kact[7]  = {0, 516, 256, 128, 64, 32, 16};
__constant__ int pk_nact[7]  = {516, 256, 128, 64, 32, 16, 2};

struct WPtrs { const float* W[7]; };

__global__ void pack_weights(WPtrs wp, u16* __restrict__ out)
{
    const int f = blockIdx.x * blockDim.x + threadIdx.x;
    if (f >= 31104) return;
    int l = 0;
    while (l < 6 && f >= pk_base8[l + 1]) ++l;
    const int r    = f - pk_base8[l];
    const int lane = r & 63;
    const int t    = r >> 6;
    const int ks   = pk_ks[l];
    const int s    = t % ks;
    const int nt   = t / ks;
    const int n    = nt * 16 + (lane & 15);
    const int k0   = s * 32 + (lane >> 4) * 8;
    const int nact = pk_nact[l];
    const int khp  = pk_khp[l];
    const int kact = pk_kact[l];
    const float* W = wp.W[l];

    union { short8 v; u16 e[8]; } frag;
#pragma unroll
    for (int j = 0; j < 8; ++j) {
        const int k = k0 + j;
        float v = 0.0f;
        if (n < nact) {
            if (k < khp) {
                if (k < kact) v = W[k * nact + n];
            } else {
                const int xr = k - khp;
                if (xr < 37) v = W[(kact + xr) * nact + n];
            }
        }
        frag.e[j] = f2bf(v);
    }
    *(short8*)(out + (size_t)f * 8) = frag.v;
}

// ---------------------------------------------------------------------------
// Channel-last repack: cl[b][x][y][slot] = plane_c[b][x][y], slot = xin col
// (ctx c -> c; lr c -> 34+c; eps -> 36; slots 32,33,37..39 zero). One block
// per (b, x): coalesced plane-row reads -> LDS transpose -> contiguous write.
// ---------------------------------------------------------------------------
struct RPk { const float* ctx; const float* lr; const float* eps; float* cl; };

__global__ void repack_cl(RPk q)
{
    __shared__ float ls[64 * CLSTRIDE];
    const int b = blockIdx.x >> 6;
    const int x = blockIdx.x & 63;
    for (int i = threadIdx.x; i < 64 * CLSTRIDE; i += 256) ls[i] = 0.f;
    __syncthreads();
    for (int i = threadIdx.x; i < 35 * 64; i += 256) {
        const int c = i / 64, y = i % 64;
        float v; int slot;
        if (c < 32)      { v = q.ctx[(((size_t)b * 32 + c) * 64 + x) * 64 + y]; slot = c; }
        else if (c < 34) { v = q.lr [(((size_t)b * 2 + (c - 32)) * 64 + x) * 64 + y]; slot = 34 + (c - 32); }
        else             { v = q.eps[(((size_t)b) * 64 + x) * 64 + y];          slot = 36; }
        ls[y * CLSTRIDE + slot] = v;
    }
    __syncthreads();
    float* out = q.cl + ((size_t)b * 64 + x) * 64 * CLSTRIDE;
    for (int i = threadIdx.x; i < 64 * CLSTRIDE; i += 256) out[i] = ls[i];
}

struct MainParams {
    const float* lr;     // [B,2,64,64]
    const float* ctx;    // [B,32,64,64]
    const float* eps;    // [B,64,64]
    const float* coord;  // [B,N,2]
    const float* Bb[7];  // biases (fp32)
    const u16*   wpack;  // packed bf16 weights in d_ws
    const float* cl;     // channel-last planes (d_ws + CLOFF), if clok
    int          clok;   // 1 -> cl path valid
    float*       out;    // [B,N,2]
};

// ---------------------------------------------------------------------------
// Store one n-tile's outputs for the wave's 2 m-tiles.
// D (swapped operands): col pt = lane&15, row n = (lane>>4)*4 + r.
// ---------------------------------------------------------------------------
template<int NACT, bool RELU>
__device__ __forceinline__ void store_nt(const f32x4* accm,   // [2] m-pair
                                         const float* __restrict__ bias,
                                         u16* __restrict__ s_act,
                                         int nt, int mbase, int lm, int lq)
{
    const int bn = nt * 16 + lq * 4;
    float bv[4];
    if (bn + 4 <= NACT) {
        const f32x4 b4 = *(const f32x4*)(bias + bn);
        bv[0] = b4[0]; bv[1] = b4[1]; bv[2] = b4[2]; bv[3] = b4[3];
    } else {
#pragma unroll
        for (int r = 0; r < 4; ++r)
            bv[r] = (bn + r < NACT) ? bias[bn + r] : 0.f;
    }
#pragma unroll
    for (int m = 0; m < 2; ++m) {
        float v[4];
#pragma unroll
        for (int r = 0; r < 4; ++r) {
            v[r] = accm[m][r] + bv[r];
            if (RELU) v[r] = fmaxf(v[r], 0.f);
        }
        uint2 o;
        o.x = cvtpk(v[0], v[1]);
        o.y = cvtpk(v[2], v[3]);
        *(uint2*)(s_act + (size_t)((mbase + m) * 16 + lm) * SROW + HSEG + bn) = o;
    }
}

// ---------------------------------------------------------------------------
// One MLP layer, (mg, ng) pair-wave mapping (r15, verified). mg=wave&1 owns
// m-tiles {2mg, 2mg+1}; ng=wave>>1 owns n-tiles {ng, ng+8, ...} < NT.
// Per K-step: 2 ds_read (A, shared across n-pair) + <=2 global loads (W,
// L1$-shared across the 2 sibling mg-waves) + <=4 MFMA (swapped: D[n,pt]).
// IPBAR: in-place layer — compute all, barrier, overwrite input.
// ---------------------------------------------------------------------------
template<int KHP, int NT, int NACT, int LBASE,
         bool XIN, bool RELU, bool GOUT, bool IPBAR>
__device__ __forceinline__ void mlayer(const u16* __restrict__ wpack,
                                       const float* __restrict__ bias,
                                       u16* __restrict__ s_act,
                                       float* __restrict__ gout, int p0,
                                       int wave, int lane)
{
    constexpr int KHS = KHP / 32;
    constexpr int KS  = KHS + (XIN ? 2 : 0);
    const int lm = lane & 15;
    const int lq = lane >> 4;
    const int mg = wave & 1;
    const int ng = wave >> 1;          // 0..7
    const int mbase = mg * 2;          // m-tiles {mbase, mbase+1}

    const u16* arow0 = s_act + (size_t)((mbase * 16) + lm) * SROW + lq * 8;
    const u16* arow1 = arow0 + (size_t)16 * SROW;
    const u16* wl = wpack + LBASE + lane * 8;

#define ABOFF(s_) (((s_) < KHS) ? (HSEG + (s_) * 32) : (XIN_OFF + ((s_) - KHS) * 32))

    if constexpr (IPBAR) {
        const int nt0 = ng, nt1 = ng + 8;
        const bool act0 = nt0 < NT;
        const bool act1 = nt1 < NT;
        f32x4 acc[2][2];
#pragma unroll
        for (int i = 0; i < 2; ++i)
#pragma unroll
            for (int m = 0; m < 2; ++m)
                acc[i][m] = (f32x4){0.f, 0.f, 0.f, 0.f};

        if (act0) {
            const u16* bp0 = wl + (size_t)nt0 * KS * 512;
            const u16* bp1 = wl + (size_t)nt1 * KS * 512;
#pragma unroll
            for (int s = 0; s < KS; ++s) {
                const int ab = ABOFF(s);
                const short8 a0 = *(const short8*)(arow0 + ab);
                const short8 a1 = *(const short8*)(arow1 + ab);
                const short8 w0 = *(const short8*)(bp0 + (size_t)s * 512);
                acc[0][0] = __builtin_amdgcn_mfma_f32_16x16x32_bf16(w0, a0, acc[0][0], 0, 0, 0);
                acc[0][1] = __builtin_amdgcn_mfma_f32_16x16x32_bf16(w0, a1, acc[0][1], 0, 0, 0);
                if (act1) {
                    const short8 w1 = *(const short8*)(bp1 + (size_t)s * 512);
                    acc[1][0] = __builtin_amdgcn_mfma_f32_16x16x32_bf16(w1, a0, acc[1][0], 0, 0, 0);
                    acc[1][1] = __builtin_amdgcn_mfma_f32_16x16x32_bf16(w1, a1, acc[1][1], 0, 0, 0);
                }
            }
        }
        __syncthreads();                   // all reads done before overwrite
        if (act0) store_nt<NACT, RELU>(acc[0], bias, s_act, nt0, mbase, lm, lq);
        if (act1) store_nt<NACT, RELU>(acc[1], bias, s_act, nt1, mbase, lm, lq);
    } else {
        for (int g = 0;; ++g) {
            const int nt0 = ng + 16 * g;
            if (nt0 >= NT) break;
            const int nt1 = nt0 + 8;
            const bool act1 = nt1 < NT;
            f32x4 acc[2][2];
#pragma unroll
            for (int i = 0; i < 2; ++i)
#pragma unroll
                for (int m = 0; m < 2; ++m)
                    acc[i][m] = (f32x4){0.f, 0.f, 0.f, 0.f};

            const u16* bp0 = wl + (size_t)nt0 * KS * 512;
            const u16* bp1 = wl + (size_t)nt1 * KS * 512;
#pragma unroll
            for (int s = 0; s < KS; ++s) {
                const int ab = ABOFF(s);
                const short8 a0 = *(const short8*)(arow0 + ab);
                const short8 a1 = *(const short8*)(arow1 + ab);
                const short8 w0 = *(const short8*)(bp0 + (size_t)s * 512);
                acc[0][0] = __builtin_amdgcn_mfma_f32_16x16x32_bf16(w0, a0, acc[0][0], 0, 0, 0);
                acc[0][1] = __builtin_amdgcn_mfma_f32_16x16x32_bf16(w0, a1, acc[0][1], 0, 0, 0);
                if (act1) {
                    const short8 w1 = *(const short8*)(bp1 + (size_t)s * 512);
                    acc[1][0] = __builtin_amdgcn_mfma_f32_16x16x32_bf16(w1, a0, acc[1][0], 0, 0, 0);
                    acc[1][1] = __builtin_amdgcn_mfma_f32_16x16x32_bf16(w1, a1, acc[1][1], 0, 0, 0);
                }
            }

            if (GOUT) {
                if (lq == 0) {             // only n=0,1 valid (NACT=2)
                    const float b0 = bias[0], b1 = bias[1];
#pragma unroll
                    for (int m = 0; m < 2; ++m) {
                        float2 o;
                        o.x = acc[0][m][0] + b0;
                        o.y = acc[0][m][1] + b1;
                        *(float2*)(gout + (size_t)(p0 + (mbase + m) * 16 + lm) * 2) = o;
                    }
                }
            } else {
                store_nt<NACT, RELU>(acc[0], bias, s_act, nt0, mbase, lm, lq);
                if (act1)
                    store_nt<NACT, RELU>(acc[1], bias, s_act, nt1, mbase, lm, lq);
            }
        }
    }
#undef ABOFF
}

__global__ __launch_bounds__(NTH, 8)   // 8 waves/EU = 32 waves/CU = 2 blocks
void cont_decoder_mfma(MainParams p)
{
    extern __shared__ u16 s_act[];         // MPTS*SROW bf16 = 78848 B
    __shared__ int   s_x0[MPTS], s_y0[MPTS];
    __shared__ float s_wx[MPTS], s_wy[MPTS];

    const int tid  = threadIdx.x;
    const int wave = tid >> 6;
    const int lane = tid & 63;
    const int p0   = blockIdx.x * MPTS;
    const int b    = p0 >> 14;             // 16384 points per batch

    // ---- zero pad regions: xin[37..64) and H tail [592..608) ----
    for (int i = tid; i < MPTS * 43; i += NTH) {
        const int pt = i / 43, c = i % 43;
        const int col = (c < 27) ? (37 + c) : (592 + (c - 27));
        s_act[pt * SROW + col] = 0;
    }

    // ---- bilinear params + coord features ----
    if (tid < MPTS) {
        const int pt = p0 + tid;
        const float cx = p.coord[2 * pt];
        const float cy = p.coord[2 * pt + 1];
        const float gx = (cx + 1.0f) * 32.0f - 0.5f;   // align_corners=False
        const float gy = (cy + 1.0f) * 32.0f - 0.5f;
        const float fx0 = floorf(gx), fy0 = floorf(gy);
        s_x0[tid] = (int)fx0;
        s_y0[tid] = (int)fy0;
        s_wx[tid] = gx - fx0;
        s_wy[tid] = gy - fy0;
        s_act[tid * SROW + 32] = f2bf(cx);
        s_act[tid * SROW + 33] = f2bf(cy);
    }
    __syncthreads();

    // ---- sample 35 channels/point (ref swaps spatial axes: g[b,c,x,y]) ----
    if (p.clok) {
        // quad fast path: one float4 quad (4 channels) per iteration.
        // 640 iters/block; 4 taps x float4 coalesced; 2 cvt_pk; b64 write.
        const float* cl = p.cl + (size_t)b * 64 * 64 * CLSTRIDE;
        for (int idx = tid; idx < MPTS * 10; idx += NTH) {
            const int t = idx / 10;
            const int q = idx % 10;

            const int   x0 = s_x0[t], y0 = s_y0[t];
            const float wx = s_wx[t], wy = s_wy[t];
            const int x1 = x0 + 1, y1 = y0 + 1;
            const bool xv0 = (x0 >= 0) & (x0 < 64);
            const bool xv1 = (x1 >= 0) & (x1 < 64);
            const bool yv0 = (y0 >= 0) & (y0 < 64);
            const bool yv1 = (y1 >= 0) & (y1 < 64);
            const int xc0 = min(max(x0, 0), 63), xc1 = min(max(x1, 0), 63);
            const int yc0 = min(max(y0, 0), 63), yc1 = min(max(y1, 0), 63);

            const float w00 = (1.0f - wx) * (1.0f - wy) * ((xv0 && yv0) ? 1.0f : 0.0f);
            const float w10 = wx * (1.0f - wy)          * ((xv1 && yv0) ? 1.0f : 0.0f);
            const float w01 = (1.0f - wx) * wy          * ((xv0 && yv1) ? 1.0f : 0.0f);
            const float w11 = wx * wy                   * ((xv1 && yv1) ? 1.0f : 0.0f);

            const int qo = q * 4;
            const f32x4 t00 = *(const f32x4*)(cl + (size_t)(xc0 * 64 + yc0) * CLSTRIDE + qo);
            const f32x4 t10 = *(const f32x4*)(cl + (size_t)(xc1 * 64 + yc0) * CLSTRIDE + qo);
            const f32x4 t01 = *(const f32x4*)(cl + (size_t)(xc0 * 64 + yc1) * CLSTRIDE + qo);
            const f32x4 t11 = *(const f32x4*)(cl + (size_t)(xc1 * 64 + yc1) * CLSTRIDE + qo);

            const f32x4 v = w00 * t00 + w10 * t10 + w01 * t01 + w11 * t11;
            const unsigned lo = cvtpk(v[0], v[1]);
            const unsigned hi = cvtpk(v[2], v[3]);

            if (q == 8) {
                // cols 32,33 are coord features (written above) — keep them;
                // write only cols 34,35 (lr channels).
                *(unsigned*)(s_act + (size_t)t * SROW + 34) = hi;
            } else {
                // q<8: cols 4q..4q+3; q==9: cols 36..39 (37..39 zeros = pad)
                uint2 o; o.x = lo; o.y = hi;
                *(uint2*)(s_act + (size_t)t * SROW + qo) = o;
            }
        }
    } else {
        // fallback: original plane-gather path (exact r15)
        for (int idx = tid; idx < MPTS * 35; idx += NTH) {
            const int t = idx / 35;
            const int c = idx % 35;
            const float* base;
            int col;
            if (c < 32)      { base = p.ctx + (size_t)(b * 32 + c) * 4096;       col = c; }
            else if (c < 34) { base = p.lr  + (size_t)(b * 2 + (c - 32)) * 4096; col = 34 + (c - 32); }
            else             { base = p.eps + (size_t)b * 4096;                   col = 36; }

            const int   x0 = s_x0[t], y0 = s_y0[t];
            const float wx = s_wx[t], wy = s_wy[t];
            const int x1 = x0 + 1, y1 = y0 + 1;
            const bool xv0 = (x0 >= 0) & (x0 < 64);
            const bool xv1 = (x1 >= 0) & (x1 < 64);
            const bool yv0 = (y0 >= 0) & (y0 < 64);
            const bool yv1 = (y1 >= 0) & (y1 < 64);
            const int xc0 = min(max(x0, 0), 63), xc1 = min(max(x1, 0), 63);
            const int yc0 = min(max(y0, 0), 63), yc1 = min(max(y1, 0), 63);

            const float w00 = (1.0f - wx) * (1.0f - wy) * ((xv0 && yv0) ? 1.0f : 0.0f);
            const float w10 = wx * (1.0f - wy)          * ((xv1 && yv0) ? 1.0f : 0.0f);
            const float w01 = (1.0f - wx) * wy          * ((xv0 && yv1) ? 1.0f : 0.0f);
            const float w11 = wx * wy                   * ((xv1 && yv1) ? 1.0f : 0.0f);

            const float val = w00 * base[xc0 * 64 + yc0]
                            + w10 * base[xc1 * 64 + yc0]
                            + w01 * base[xc0 * 64 + yc1]
                            + w11 * base[xc1 * 64 + yc1];
            s_act[t * SROW + col] = f2bf(val);
        }
    }
    __syncthreads();

    // ---- MLP:  xin(37p64) ->W0-> H(516p544) ->W1-> H(256) ->W2-> H(128)
    //            ->W3-> H(64) ->W4-> H(32) ->W5-> H(16) ->W6-> out(2)
    //     KHP  NT  NACT LBASE    XIN    RELU   GOUT   IPBAR
    mlayer<  0, 33, 516, 0,      true,  true,  false, false>(p.wpack, p.Bb[0], s_act, nullptr, p0, wave, lane);
    __syncthreads();
    mlayer<544, 16, 256, 33792,  true,  true,  false, true >(p.wpack, p.Bb[1], s_act, nullptr, p0, wave, lane);
    __syncthreads();
    mlayer<256,  8, 128, 189440, true,  true,  false, true >(p.wpack, p.Bb[2], s_act, nullptr, p0, wave, lane);
    __syncthreads();
    mlayer<128,  4,  64, 230400, true,  true,  false, true >(p.wpack, p.Bb[3], s_act, nullptr, p0, wave, lane);
    __syncthreads();
    mlayer< 64,  2,  32, 242688, true,  true,  false, true >(p.wpack, p.Bb[4], s_act, nullptr, p0, wave, lane);
    __syncthreads();
    mlayer< 32,  1,  16, 246784, true,  true,  false, true >(p.wpack, p.Bb[5], s_act, nullptr, p0, wave, lane);
    __syncthreads();
    mlayer< 32,  1,   2, 248320, false, false, true,  false>(p.wpack, p.Bb[6], s_act, p.out,   p0, wave, lane);
}

extern "C" void kernel_launch(void* const* d_in, const int* in_sizes, int n_in,
                              void* d_out, int out_size, void* d_ws, size_t ws_size,
                              hipStream_t stream)
{
    WPtrs wp;
    for (int l = 0; l < 7; ++l) wp.W[l] = (const float*)d_in[4 + 2 * l];

    const size_t cl_bytes = (size_t)8 * 64 * 64 * CLSTRIDE * 4;   // 5.24 MB
    const bool clok = ws_size >= (size_t)CLOFF + cl_bytes;

    MainParams p;
    p.lr    = (const float*)d_in[0];
    p.ctx   = (const float*)d_in[1];
    p.eps   = (const float*)d_in[2];
    p.coord = (const float*)d_in[3];
    for (int l = 0; l < 7; ++l) p.Bb[l] = (const float*)d_in[5 + 2 * l];
    p.wpack = (const u16*)d_ws;
    p.cl    = (const float*)((const char*)d_ws + CLOFF);
    p.clok  = clok ? 1 : 0;
    p.out   = (float*)d_out;

    // Opt in to large dynamic LDS (idempotent; not a stream op, capture-safe).
    hipFuncSetAttribute((const void*)cont_decoder_mfma,
                        hipFuncAttributeMaxDynamicSharedMemorySize, LDSBYTES);

    hipLaunchKernelGGL(pack_weights, dim3(122), dim3(256), 0, stream, wp, (u16*)d_ws);
    if (clok) {
        RPk q;
        q.ctx = p.ctx; q.lr = p.lr; q.eps = p.eps;
        q.cl  = (float*)((char*)d_ws + CLOFF);
        hipLaunchKernelGGL(repack_cl, dim3(512), dim3(256), 0, stream, q);
    }
    hipLaunchKernelGGL(cont_decoder_mfma, dim3(GRIDX), dim3(NTH), LDSBYTES, stream, p);
}

// Round 17
// 179.984 us; speedup vs baseline: 1.4133x; 1.0243x over previous
//
#include <hip/hip_runtime.h>

// ============================================================================
// ContDecoder on MI355X — bf16 MFMA, round 19: ping-pong segments (-4
// internal barriers) + double-quad sampling (half the LDS writes) + merged
// prep kernel. Base = r18 (98.5us main).
//
// Ledger at 98.5us: LDS port ~85% committed (2100 LDS instrs/block x16
// blocks/CU); deeper A-sharing VGPR-blocked (NPW=4 needs 66 > 64 cap).
// r19 cuts LDS instrs + barriers without touching the closed mapping space:
//   (1) ping-pong: L2..L6 write disjoint H sub-segments -> no internal
//       barrier (only L1, which reads all 544, keeps in-place+barrier).
//       Segments: L1 out [64,320) | L2 [320,448) | L3 [64,128) |
//       L4 [448,480) | L5 [128,144); L6 reads [128,160) (16 stale x 0).
//   (2) sampling double-quads: 8 channels/iter, one b128 write; 320 iters
//       (was 640): write instrs and bilinear VALU halved.
//   (3) pack_weights + repack_cl merged into one prep kernel (one launch).
// Kept: r15 pair-wave mapping, in-place row [xin 0..64 | H 64..608 | 616),
// channel-last CLSTRIDE=40 repack, cvt_pk epilogue, 16x16x32 pack.
// ============================================================================

#define NTH     1024
#define NWAVES  16
#define MPTS    64              // points per block (4 m-tiles of 16)
#define MTILES  (MPTS / 16)
#define SROW    616             // LDS row stride in bf16 elems (1232 B)
#define XIN_OFF 0
#define NPOINTS (8 * 16384)
#define GRIDX   (NPOINTS / MPTS)   // 2048 blocks
#define LDSBYTES (MPTS * SROW * 2) // 78848 -> 2 blocks/CU
#define CLSTRIDE 40             // channel-last inner stride (floats)
#define CLOFF   524288          // byte offset of channel-last block in d_ws

typedef short          short8  __attribute__((ext_vector_type(8)));
typedef float          f32x4   __attribute__((ext_vector_type(4)));
typedef unsigned int   u32x4   __attribute__((ext_vector_type(4)));
typedef unsigned short u16;

__device__ __forceinline__ u16 f2bf(float f) {
    unsigned int u = __builtin_bit_cast(unsigned int, f);
    u += 0x7fffu + ((u >> 16) & 1u);        // round-to-nearest-even
    return (u16)(u >> 16);
}

// packed RNE f32x2 -> bf16x2 (dst.lo = bf16(a), dst.hi = bf16(b))
__device__ __forceinline__ unsigned cvtpk(float a, float b) {
    unsigned r;
    asm("v_cvt_pk_bf16_f32 %0, %1, %2" : "=v"(r) : "v"(a), "v"(b));
    return r;
}

// ---------------------------------------------------------------------------
// Packed-weight geometry (16B fragments of 8 bf16). frag (l, nt, s, lane)
// holds B[s*32 + (lane>>4)*8 + j][nt*16 + (lane&15)], j=0..7, zero-padded
// outside (kact, nact) — zero k-rows mask stale in-place/ping-pong data.
// Identical pack as r4..r18 (HW-verified swapped-operand layout).
//   l : KHpad KSteps Ntiles  frag_base
//   0 :    0    2     33        0
//   1 :  544   19     16     4224
//   2 :  256   10      8    23680
//   3 :  128    6      4    28800
//   4 :   64    4      2    30336
//   5 :   32    3      1    30848
//   6 :   32    1      1    31040   total 31104 frags = 497664 B in d_ws
// ---------------------------------------------------------------------------
__constant__ int pk_base8[8] = {0, 4224, 23680, 28800, 30336, 30848, 31040, 31104};
__constant__ int pk_ks[7]    = {2, 19, 10, 6, 4, 3, 1};
__constant__ int pk_khp[7]   = {0, 544, 256, 128, 64, 32, 32};
__constant__ int pk_kact[7]  = {0, 516, 256, 128, 64, 32, 16};
__constant__ int pk_nact[7]  = {516, 256, 128, 64, 32, 16, 2};

struct WPtrs { const float* W[7]; };
struct RPk { const float* ctx; const float* lr; const float* eps; float* cl; };

// ---------------------------------------------------------------------------
// Merged prep: blocks [0,122) pack weights; blocks [122, 122+512) repack
// ctx/lr/eps into channel-last [b][x][y][40] fp32 (slot = xin col; 32,33,
// 37..39 zero). One launch instead of two.
// ---------------------------------------------------------------------------
__global__ void prep_ws(WPtrs wp, RPk q, u16* __restrict__ out, int clok)
{
    __shared__ float ls[64 * CLSTRIDE];

    if (blockIdx.x < 122) {
        const int f = blockIdx.x * blockDim.x + threadIdx.x;
        if (f >= 31104) return;
        int l = 0;
        while (l < 6 && f >= pk_base8[l + 1]) ++l;
        const int r    = f - pk_base8[l];
        const int lane = r & 63;
        const int t    = r >> 6;
        const int ks   = pk_ks[l];
        const int s    = t % ks;
        const int nt   = t / ks;
        const int n    = nt * 16 + (lane & 15);
        const int k0   = s * 32 + (lane >> 4) * 8;
        const int nact = pk_nact[l];
        const int khp  = pk_khp[l];
        const int kact = pk_kact[l];
        const float* W = wp.W[l];

        union { short8 v; u16 e[8]; } frag;
#pragma unroll
        for (int j = 0; j < 8; ++j) {
            const int k = k0 + j;
            float v = 0.0f;
            if (n < nact) {
                if (k < khp) {
                    if (k < kact) v = W[k * nact + n];
                } else {
                    const int xr = k - khp;
                    if (xr < 37) v = W[(kact + xr) * nact + n];
                }
            }
            frag.e[j] = f2bf(v);
        }
        *(short8*)(out + (size_t)f * 8) = frag.v;
    } else {
        if (!clok) return;
        const int bx = blockIdx.x - 122;
        const int b = bx >> 6;
        const int x = bx & 63;
        for (int i = threadIdx.x; i < 64 * CLSTRIDE; i += 256) ls[i] = 0.f;
        __syncthreads();
        for (int i = threadIdx.x; i < 35 * 64; i += 256) {
            const int c = i / 64, y = i % 64;
            float v; int slot;
            if (c < 32)      { v = q.ctx[(((size_t)b * 32 + c) * 64 + x) * 64 + y]; slot = c; }
            else if (c < 34) { v = q.lr [(((size_t)b * 2 + (c - 32)) * 64 + x) * 64 + y]; slot = 34 + (c - 32); }
            else             { v = q.eps[(((size_t)b) * 64 + x) * 64 + y];          slot = 36; }
            ls[y * CLSTRIDE + slot] = v;
        }
        __syncthreads();
        float* o = q.cl + ((size_t)b * 64 + x) * 64 * CLSTRIDE;
        for (int i = threadIdx.x; i < 64 * CLSTRIDE; i += 256) o[i] = ls[i];
    }
}

struct MainParams {
    const float* lr;     // [B,2,64,64]
    const float* ctx;    // [B,32,64,64]
    const float* eps;    // [B,64,64]
    const float* coord;  // [B,N,2]
    const float* Bb[7];  // biases (fp32)
    const u16*   wpack;  // packed bf16 weights in d_ws
    const float* cl;     // channel-last planes (d_ws + CLOFF), if clok
    int          clok;   // 1 -> cl path valid
    float*       out;    // [B,N,2]
};

// ---------------------------------------------------------------------------
// Store one n-tile's outputs (at segment base OS) for the wave's 2 m-tiles.
// D (swapped operands): col pt = lane&15, row n = (lane>>4)*4 + r.
// ---------------------------------------------------------------------------
template<int OS, int NACT, bool RELU>
__device__ __forceinline__ void store_nt(const f32x4* accm,   // [2] m-pair
                                         const float* __restrict__ bias,
                                         u16* __restrict__ s_act,
                                         int nt, int mbase, int lm, int lq)
{
    const int bn = nt * 16 + lq * 4;
    float bv[4];
    if (bn + 4 <= NACT) {
        const f32x4 b4 = *(const f32x4*)(bias + bn);
        bv[0] = b4[0]; bv[1] = b4[1]; bv[2] = b4[2]; bv[3] = b4[3];
    } else {
#pragma unroll
        for (int r = 0; r < 4; ++r)
            bv[r] = (bn + r < NACT) ? bias[bn + r] : 0.f;
    }
#pragma unroll
    for (int m = 0; m < 2; ++m) {
        float v[4];
#pragma unroll
        for (int r = 0; r < 4; ++r) {
            v[r] = accm[m][r] + bv[r];
            if (RELU) v[r] = fmaxf(v[r], 0.f);
        }
        uint2 o;
        o.x = cvtpk(v[0], v[1]);
        o.y = cvtpk(v[2], v[3]);
        *(uint2*)(s_act + (size_t)((mbase + m) * 16 + lm) * SROW + OS + bn) = o;
    }
}

// ---------------------------------------------------------------------------
// One MLP layer, (mg, ng) pair-wave mapping (r15-verified). mg=wave&1 owns
// m-tiles {2mg, 2mg+1}; ng=wave>>1 owns n-tiles {ng, ng+8} < NT (L0: +16g).
// Per K-step: 2 ds_read (A from segment HS / xin) + <=2 global loads (W) +
// <=4 MFMA (swapped: D[n,pt]). IPBAR (L1 only): compute -> barrier -> write
// over input. Other layers: OS disjoint from HS+xin -> direct store.
// ---------------------------------------------------------------------------
template<int KHP, int HS, int OS, int NT, int NACT, int LBASE,
         bool XIN, bool RELU, bool GOUT, bool IPBAR>
__device__ __forceinline__ void mlayer(const u16* __restrict__ wpack,
                                       const float* __restrict__ bias,
                                       u16* __restrict__ s_act,
                                       float* __restrict__ gout, int p0,
                                       int wave, int lane)
{
    constexpr int KHS = KHP / 32;
    constexpr int KS  = KHS + (XIN ? 2 : 0);
    const int lm = lane & 15;
    const int lq = lane >> 4;
    const int mg = wave & 1;
    const int ng = wave >> 1;          // 0..7
    const int mbase = mg * 2;          // m-tiles {mbase, mbase+1}

    const u16* arow0 = s_act + (size_t)((mbase * 16) + lm) * SROW + lq * 8;
    const u16* arow1 = arow0 + (size_t)16 * SROW;
    const u16* wl = wpack + LBASE + lane * 8;

#define ABOFF(s_) (((s_) < KHS) ? (HS + (s_) * 32) : (XIN_OFF + ((s_) - KHS) * 32))

    if constexpr (NT > 16) {
        // L0: g-loop over pairs {ng+16g, ng+8+16g}
        for (int g = 0;; ++g) {
            const int nt0 = ng + 16 * g;
            if (nt0 >= NT) break;
            const int nt1 = nt0 + 8;
            const bool act1 = nt1 < NT;
            f32x4 acc[2][2];
#pragma unroll
            for (int i = 0; i < 2; ++i)
#pragma unroll
                for (int m = 0; m < 2; ++m)
                    acc[i][m] = (f32x4){0.f, 0.f, 0.f, 0.f};

            const u16* bp0 = wl + (size_t)nt0 * KS * 512;
            const u16* bp1 = wl + (size_t)nt1 * KS * 512;
#pragma unroll
            for (int s = 0; s < KS; ++s) {
                const int ab = ABOFF(s);
                const short8 a0 = *(const short8*)(arow0 + ab);
                const short8 a1 = *(const short8*)(arow1 + ab);
                const short8 w0 = *(const short8*)(bp0 + (size_t)s * 512);
                acc[0][0] = __builtin_amdgcn_mfma_f32_16x16x32_bf16(w0, a0, acc[0][0], 0, 0, 0);
                acc[0][1] = __builtin_amdgcn_mfma_f32_16x16x32_bf16(w0, a1, acc[0][1], 0, 0, 0);
                if (act1) {
                    const short8 w1 = *(const short8*)(bp1 + (size_t)s * 512);
                    acc[1][0] = __builtin_amdgcn_mfma_f32_16x16x32_bf16(w1, a0, acc[1][0], 0, 0, 0);
                    acc[1][1] = __builtin_amdgcn_mfma_f32_16x16x32_bf16(w1, a1, acc[1][1], 0, 0, 0);
                }
            }
            store_nt<OS, NACT, RELU>(acc[0], bias, s_act, nt0, mbase, lm, lq);
            if (act1)
                store_nt<OS, NACT, RELU>(acc[1], bias, s_act, nt1, mbase, lm, lq);
        }
    } else {
        // single pair {ng, ng+8}
        const int nt0 = ng, nt1 = ng + 8;
        const bool act0 = nt0 < NT;
        const bool act1 = nt1 < NT;
        f32x4 acc[2][2];
#pragma unroll
        for (int i = 0; i < 2; ++i)
#pragma unroll
            for (int m = 0; m < 2; ++m)
                acc[i][m] = (f32x4){0.f, 0.f, 0.f, 0.f};

        if (act0) {
            const u16* bp0 = wl + (size_t)nt0 * KS * 512;
            const u16* bp1 = wl + (size_t)nt1 * KS * 512;
#pragma unroll
            for (int s = 0; s < KS; ++s) {
                const int ab = ABOFF(s);
                const short8 a0 = *(const short8*)(arow0 + ab);
                const short8 a1 = *(const short8*)(arow1 + ab);
                const short8 w0 = *(const short8*)(bp0 + (size_t)s * 512);
                acc[0][0] = __builtin_amdgcn_mfma_f32_16x16x32_bf16(w0, a0, acc[0][0], 0, 0, 0);
                acc[0][1] = __builtin_amdgcn_mfma_f32_16x16x32_bf16(w0, a1, acc[0][1], 0, 0, 0);
                if (act1) {
                    const short8 w1 = *(const short8*)(bp1 + (size_t)s * 512);
                    acc[1][0] = __builtin_amdgcn_mfma_f32_16x16x32_bf16(w1, a0, acc[1][0], 0, 0, 0);
                    acc[1][1] = __builtin_amdgcn_mfma_f32_16x16x32_bf16(w1, a1, acc[1][1], 0, 0, 0);
                }
            }
        }
        if constexpr (IPBAR) __syncthreads();   // in-place: reads drained
        if (GOUT) {
            if (act0 && lq == 0) {             // only n=0,1 valid (NACT=2)
                const float b0 = bias[0], b1 = bias[1];
#pragma unroll
                for (int m = 0; m < 2; ++m) {
                    float2 o;
                    o.x = acc[0][m][0] + b0;
                    o.y = acc[0][m][1] + b1;
                    *(float2*)(gout + (size_t)(p0 + (mbase + m) * 16 + lm) * 2) = o;
                }
            }
        } else {
            if (act0) store_nt<OS, NACT, RELU>(acc[0], bias, s_act, nt0, mbase, lm, lq);
            if (act1) store_nt<OS, NACT, RELU>(acc[1], bias, s_act, nt1, mbase, lm, lq);
        }
    }
#undef ABOFF
}

__global__ __launch_bounds__(NTH, 8)   // 8 waves/EU = 32 waves/CU = 2 blocks
void cont_decoder_mfma(MainParams p)
{
    extern __shared__ u16 s_act[];         // MPTS*SROW bf16 = 78848 B
    __shared__ int   s_x0[MPTS], s_y0[MPTS];
    __shared__ float s_wx[MPTS], s_wy[MPTS];

    const int tid  = threadIdx.x;
    const int wave = tid >> 6;
    const int lane = tid & 63;
    const int p0   = blockIdx.x * MPTS;
    const int b    = p0 >> 14;             // 16384 points per batch

    // ---- zero pad regions: xin[37..64) and H tail [592..608) ----
    for (int i = tid; i < MPTS * 43; i += NTH) {
        const int pt = i / 43, c = i % 43;
        const int col = (c < 27) ? (37 + c) : (592 + (c - 27));
        s_act[pt * SROW + col] = 0;
    }

    // ---- bilinear params + coord features ----
    if (tid < MPTS) {
        const int pt = p0 + tid;
        const float cx = p.coord[2 * pt];
        const float cy = p.coord[2 * pt + 1];
        const float gx = (cx + 1.0f) * 32.0f - 0.5f;   // align_corners=False
        const float gy = (cy + 1.0f) * 32.0f - 0.5f;
        const float fx0 = floorf(gx), fy0 = floorf(gy);
        s_x0[tid] = (int)fx0;
        s_y0[tid] = (int)fy0;
        s_wx[tid] = gx - fx0;
        s_wy[tid] = gy - fy0;
        s_act[tid * SROW + 32] = f2bf(cx);
        s_act[tid * SROW + 33] = f2bf(cy);
    }
    __syncthreads();

    // ---- sample 35 channels/point (ref swaps spatial axes: g[b,c,x,y]) ----
    if (p.clok) {
        // double-quad fast path: 8 channels/iter, 320 iters/block,
        // one b128 LDS write (or the 34..39 tail pair for it==4).
        const float* cl = p.cl + (size_t)b * 64 * 64 * CLSTRIDE;
        for (int idx = tid; idx < MPTS * 5; idx += NTH) {
            const int t  = idx / 5;
            const int it = idx % 5;

            const int   x0 = s_x0[t], y0 = s_y0[t];
            const float wx = s_wx[t], wy = s_wy[t];
            const int x1 = x0 + 1, y1 = y0 + 1;
            const bool xv0 = (x0 >= 0) & (x0 < 64);
            const bool xv1 = (x1 >= 0) & (x1 < 64);
            const bool yv0 = (y0 >= 0) & (y0 < 64);
            const bool yv1 = (y1 >= 0) & (y1 < 64);
            const int xc0 = min(max(x0, 0), 63), xc1 = min(max(x1, 0), 63);
            const int yc0 = min(max(y0, 0), 63), yc1 = min(max(y1, 0), 63);

            const float w00 = (1.0f - wx) * (1.0f - wy) * ((xv0 && yv0) ? 1.0f : 0.0f);
            const float w10 = wx * (1.0f - wy)          * ((xv1 && yv0) ? 1.0f : 0.0f);
            const float w01 = (1.0f - wx) * wy          * ((xv0 && yv1) ? 1.0f : 0.0f);
            const float w11 = wx * wy                   * ((xv1 && yv1) ? 1.0f : 0.0f);

            const float* c00 = cl + (size_t)(xc0 * 64 + yc0) * CLSTRIDE;
            const float* c10 = cl + (size_t)(xc1 * 64 + yc0) * CLSTRIDE;
            const float* c01 = cl + (size_t)(xc0 * 64 + yc1) * CLSTRIDE;
            const float* c11 = cl + (size_t)(xc1 * 64 + yc1) * CLSTRIDE;

            const int qo = it * 8;
            const f32x4 v0 = w00 * *(const f32x4*)(c00 + qo)
                           + w10 * *(const f32x4*)(c10 + qo)
                           + w01 * *(const f32x4*)(c01 + qo)
                           + w11 * *(const f32x4*)(c11 + qo);
            const f32x4 v1 = w00 * *(const f32x4*)(c00 + qo + 4)
                           + w10 * *(const f32x4*)(c10 + qo + 4)
                           + w01 * *(const f32x4*)(c01 + qo + 4)
                           + w11 * *(const f32x4*)(c11 + qo + 4);

            if (it == 4) {
                // cols 32,33 = coord features (keep); write 34,35 + 36..39
                *(unsigned*)(s_act + (size_t)t * SROW + 34) = cvtpk(v0[2], v0[3]);
                uint2 o;
                o.x = cvtpk(v1[0], v1[1]);
                o.y = cvtpk(v1[2], v1[3]);
                *(uint2*)(s_act + (size_t)t * SROW + 36) = o;
            } else {
                u32x4 o;
                o.x = cvtpk(v0[0], v0[1]);
                o.y = cvtpk(v0[2], v0[3]);
                o.z = cvtpk(v1[0], v1[1]);
                o.w = cvtpk(v1[2], v1[3]);
                *(u32x4*)(s_act + (size_t)t * SROW + qo) = o;  // 16B aligned
            }
        }
    } else {
        // fallback: original plane-gather path
        for (int idx = tid; idx < MPTS * 35; idx += NTH) {
            const int t = idx / 35;
            const int c = idx % 35;
            const float* base;
            int col;
            if (c < 32)      { base = p.ctx + (size_t)(b * 32 + c) * 4096;       col = c; }
            else if (c < 34) { base = p.lr  + (size_t)(b * 2 + (c - 32)) * 4096; col = 34 + (c - 32); }
            else             { base = p.eps + (size_t)b * 4096;                   col = 36; }

            const int   x0 = s_x0[t], y0 = s_y0[t];
            const float wx = s_wx[t], wy = s_wy[t];
            const int x1 = x0 + 1, y1 = y0 + 1;
            const bool xv0 = (x0 >= 0) & (x0 < 64);
            const bool xv1 = (x1 >= 0) & (x1 < 64);
            const bool yv0 = (y0 >= 0) & (y0 < 64);
            const bool yv1 = (y1 >= 0) & (y1 < 64);
            const int xc0 = min(max(x0, 0), 63), xc1 = min(max(x1, 0), 63);
            const int yc0 = min(max(y0, 0), 63), yc1 = min(max(y1, 0), 63);

            const float w00 = (1.0f - wx) * (1.0f - wy) * ((xv0 && yv0) ? 1.0f : 0.0f);
            const float w10 = wx * (1.0f - wy)          * ((xv1 && yv0) ? 1.0f : 0.0f);
            const float w01 = (1.0f - wx) * wy          * ((xv0 && yv1) ? 1.0f : 0.0f);
            const float w11 = wx * wy                   * ((xv1 && yv1) ? 1.0f : 0.0f);

            const float val = w00 * base[xc0 * 64 + yc0]
                            + w10 * base[xc1 * 64 + yc0]
                            + w01 * base[xc0 * 64 + yc1]
                            + w11 * base[xc1 * 64 + yc1];
            s_act[t * SROW + col] = f2bf(val);
        }
    }
    __syncthreads();

    // ---- MLP (ping-pong segments; only L1 in-place):
    //   L0: xin -> [64,592)        L1: [64,608)+xin -> [64,320)  (in-place)
    //   L2: [64,320)+xin -> [320,448)   L3: [320,448)+xin -> [64,128)
    //   L4: [64,128)+xin -> [448,480)   L5: [448,480)+xin -> [128,144)
    //   L6: [128,160) (16 stale x 0) -> out
    //     KHP  HS   OS   NT  NACT LBASE    XIN    RELU   GOUT   IPBAR
    mlayer<  0,  64,  64, 33, 516, 0,      true,  true,  false, false>(p.wpack, p.Bb[0], s_act, nullptr, p0, wave, lane);
    __syncthreads();
    mlayer<544,  64,  64, 16, 256, 33792,  true,  true,  false, true >(p.wpack, p.Bb[1], s_act, nullptr, p0, wave, lane);
    __syncthreads();
    mlayer<256,  64, 320,  8, 128, 189440, true,  true,  false, false>(p.wpack, p.Bb[2], s_act, nullptr, p0, wave, lane);
    __syncthreads();
    mlayer<128, 320,  64,  4,  64, 230400, true,  true,  false, false>(p.wpack, p.Bb[3], s_act, nullptr, p0, wave, lane);
    __syncthreads();
    mlayer< 64,  64, 448,  2,  32, 242688, true,  true,  false, false>(p.wpack, p.Bb[4], s_act, nullptr, p0, wave, lane);
    __syncthreads();
    mlayer< 32, 448, 128,  1,  16, 246784, true,  true,  false, false>(p.wpack, p.Bb[5], s_act, nullptr, p0, wave, lane);
    __syncthreads();
    mlayer< 32, 128,   0,  1,   2, 248320, false, false, true,  false>(p.wpack, p.Bb[6], s_act, p.out,   p0, wave, lane);
}

extern "C" void kernel_launch(void* const* d_in, const int* in_sizes, int n_in,
                              void* d_out, int out_size, void* d_ws, size_t ws_size,
                              hipStream_t stream)
{
    WPtrs wp;
    for (int l = 0; l < 7; ++l) wp.W[l] = (const float*)d_in[4 + 2 * l];

    const size_t cl_bytes = (size_t)8 * 64 * 64 * CLSTRIDE * 4;   // 5.24 MB
    const bool clok = ws_size >= (size_t)CLOFF + cl_bytes;

    MainParams p;
    p.lr    = (const float*)d_in[0];
    p.ctx   = (const float*)d_in[1];
    p.eps   = (const float*)d_in[2];
    p.coord = (const float*)d_in[3];
    for (int l = 0; l < 7; ++l) p.Bb[l] = (const float*)d_in[5 + 2 * l];
    p.wpack = (const u16*)d_ws;
    p.cl    = (const float*)((const char*)d_ws + CLOFF);
    p.clok  = clok ? 1 : 0;
    p.out   = (float*)d_out;

    RPk q;
    q.ctx = p.ctx; q.lr = p.lr; q.eps = p.eps;
    q.cl  = (float*)((char*)d_ws + CLOFF);

    // Opt in to large dynamic LDS (idempotent; not a stream op, capture-safe).
    hipFuncSetAttribute((const void*)cont_decoder_mfma,
                        hipFuncAttributeMaxDynamicSharedMemorySize, LDSBYTES);

    hipLaunchKernelGGL(prep_ws, dim3(122 + 512), dim3(256), 0, stream,
                       wp, q, (u16*)d_ws, clok ? 1 : 0);
    hipLaunchKernelGGL(cont_decoder_mfma, dim3(GRIDX), dim3(NTH), LDSBYTES, stream, p);
}